// Round 9
// baseline (658.359 us; speedup 1.0000x reference)
//
#include <hip/hip_runtime.h>
#include <hip/hip_bf16.h>

typedef __hip_bfloat16 bf16_t;
typedef short bf16x8 __attribute__((ext_vector_type(8)));
typedef float f32x4 __attribute__((ext_vector_type(4)));

#define NROW 8192
#define LEAKY 0.2f

__device__ __forceinline__ float b2f(bf16_t v){ return __bfloat162float(v); }
__device__ __forceinline__ unsigned short f2b(float f){
  union { bf16_t h; unsigned short u; } cv; cv.h = __float2bfloat16(f); return cv.u;
}
__device__ __forceinline__ float sigf(float v){ return 1.0f / (1.0f + __expf(-v)); }

__device__ __forceinline__ unsigned char packf(float4 v0, float4 v1){
  return (unsigned char)(
      (unsigned int)(v0.x>0.f)      | ((unsigned int)(v0.y>0.f)<<1) |
      ((unsigned int)(v0.z>0.f)<<2) | ((unsigned int)(v0.w>0.f)<<3) |
      ((unsigned int)(v1.x>0.f)<<4) | ((unsigned int)(v1.y>0.f)<<5) |
      ((unsigned int)(v1.z>0.f)<<6) | ((unsigned int)(v1.w>0.f)<<7));
}
__device__ __forceinline__ unsigned char packb(bf16x8 v){
  unsigned int m = 0;
  #pragma unroll
  for (int j=0;j<8;++j){
    union { short s; unsigned short u; } cv; cv.s = v[j];
    m |= ((unsigned int)(cv.u > 0 && cv.u < 0x8000)) << j;
  }
  return (unsigned char)m;
}

// ---------------------------------------------------------------------------
// K0: dtype probe. flag[0] = 1 if inputs are float32, 0 if bf16.
// ---------------------------------------------------------------------------
__global__ void k_probe(const unsigned short* __restrict__ x_raw, int* __restrict__ flag)
{
  const int lane = threadIdx.x;
  int cnt = 0;
  for (int k = lane; k < 512; k += 64){
    const int e = (x_raw[k] >> 7) & 0xff;
    cnt += (e >= 120 && e <= 130) ? 1 : 0;
  }
  #pragma unroll
  for (int s = 1; s < 64; s <<= 1) cnt += __shfl_xor(cnt, s, 64);
  if (lane == 0) flag[0] = (cnt < 384) ? 1 : 0;
}

// ---------------------------------------------------------------------------
// K1: weight converts to bf16: enc_W_ih (256x128), dec_W_ih (512x64).
// ---------------------------------------------------------------------------
__global__ __launch_bounds__(256) void k_cvt(
    const void* __restrict__ encW, const void* __restrict__ decW,
    const int* __restrict__ flag,
    unsigned short* __restrict__ encWb, unsigned short* __restrict__ decWb)
{
  const int idx = blockIdx.x*256 + threadIdx.x;
  const int isf32 = flag[0];
  if (idx < 32768){
    float v = isf32 ? ((const float*)encW)[idx] : b2f(((const bf16_t*)encW)[idx]);
    encWb[idx] = f2b(v);
  } else {
    const int j = idx - 32768;
    float v = isf32 ? ((const float*)decW)[j] : b2f(((const bf16_t*)decW)[j]);
    decWb[j] = f2b(v);
  }
}

// ---------------------------------------------------------------------------
// K2 v2: fea+mask, ONE ROW PER WAVE (2048 blocks x 4 waves), barrier-free.
// Each wave: issue mask-load chunks 0,1 (2-ahead pipeline) -> fea dependent
// chain (hides latency) -> pack c / issue c+2 rotation. All waves symmetric
// (no wave-0 serialization). Static register buffers (full unroll).
// ---------------------------------------------------------------------------
__global__ __launch_bounds__(256) void k_feamask4(
    const void* __restrict__ x, const void* __restrict__ adj,
    const void* __restrict__ fea_W, const void* __restrict__ fea_b,
    const void* __restrict__ gat_W, const void* __restrict__ gat_a,
    const int* __restrict__ flag,
    unsigned short* __restrict__ Whb_p, float* __restrict__ s1, float* __restrict__ s2,
    unsigned short* __restrict__ xb, unsigned char* __restrict__ mask8)
{
  const int tid = threadIdx.x;
  const int wv  = tid >> 6;
  const int l   = tid & 63;
  const int row = blockIdx.x * 4 + wv;
  const int isf32 = flag[0];

  unsigned char* mrow = mask8 + (size_t)row * 1024;

  // ---- issue chunks 0 and 1 (8 or 16 loads in flight) ----------------------
  float4 vA0,vA1,vA2,vA3, vB0,vB1,vB2,vB3;     // chunk even buffers (f32)
  float4 wA0,wA1,wA2,wA3, wB0,wB1,wB2,wB3;     // chunk odd buffers  (f32)
  bf16x8 q0,q1,q2,q3, p0,p1,p2,p3;             // bf16 buffers
  const float4* a4 = (const float4*)((const float*)adj + (size_t)row*NROW);
  const unsigned short* a2 = (const unsigned short*)adj + (size_t)row*NROW;

  if (isf32){
    vA0 = a4[(size_t)((0*4+0)*64 + l)*2]; vB0 = a4[(size_t)((0*4+0)*64 + l)*2 + 1];
    vA1 = a4[(size_t)((0*4+1)*64 + l)*2]; vB1 = a4[(size_t)((0*4+1)*64 + l)*2 + 1];
    vA2 = a4[(size_t)((0*4+2)*64 + l)*2]; vB2 = a4[(size_t)((0*4+2)*64 + l)*2 + 1];
    vA3 = a4[(size_t)((0*4+3)*64 + l)*2]; vB3 = a4[(size_t)((0*4+3)*64 + l)*2 + 1];
    wA0 = a4[(size_t)((1*4+0)*64 + l)*2]; wB0 = a4[(size_t)((1*4+0)*64 + l)*2 + 1];
    wA1 = a4[(size_t)((1*4+1)*64 + l)*2]; wB1 = a4[(size_t)((1*4+1)*64 + l)*2 + 1];
    wA2 = a4[(size_t)((1*4+2)*64 + l)*2]; wB2 = a4[(size_t)((1*4+2)*64 + l)*2 + 1];
    wA3 = a4[(size_t)((1*4+3)*64 + l)*2]; wB3 = a4[(size_t)((1*4+3)*64 + l)*2 + 1];
  } else {
    q0 = *(const bf16x8*)(a2 + (size_t)((0*4+0)*64 + l)*8);
    q1 = *(const bf16x8*)(a2 + (size_t)((0*4+1)*64 + l)*8);
    q2 = *(const bf16x8*)(a2 + (size_t)((0*4+2)*64 + l)*8);
    q3 = *(const bf16x8*)(a2 + (size_t)((0*4+3)*64 + l)*8);
    p0 = *(const bf16x8*)(a2 + (size_t)((1*4+0)*64 + l)*8);
    p1 = *(const bf16x8*)(a2 + (size_t)((1*4+1)*64 + l)*8);
    p2 = *(const bf16x8*)(a2 + (size_t)((1*4+2)*64 + l)*8);
    p3 = *(const bf16x8*)(a2 + (size_t)((1*4+3)*64 + l)*8);
  }

  // ---- fea for this wave's row (dependent chain hides chunk 0/1 latency) ---
  {
    float x0, x1;
    if (isf32){
      const float* xr = (const float*)x + (size_t)row*128;
      x0 = xr[l]; x1 = xr[l+64];
    } else {
      const bf16_t* xr = (const bf16_t*)x + (size_t)row*128;
      x0 = b2f(xr[l]); x1 = b2f(xr[l+64]);
    }
    xb[(size_t)row*128 + l]      = f2b(x0);
    xb[(size_t)row*128 + 64 + l] = f2b(x1);

    float acc = isf32 ? ((const float*)fea_b)[l] : b2f(((const bf16_t*)fea_b)[l]);
    if (isf32){
      const float* W = (const float*)fea_W;
      #pragma unroll
      for (int d=0; d<64; ++d) acc = fmaf(__shfl(x0, d, 64), W[d*64+l], acc);
      #pragma unroll
      for (int d=0; d<64; ++d) acc = fmaf(__shfl(x1, d, 64), W[(d+64)*64+l], acc);
    } else {
      const bf16_t* W = (const bf16_t*)fea_W;
      #pragma unroll
      for (int d=0; d<64; ++d) acc = fmaf(__shfl(x0, d, 64), b2f(W[d*64+l]), acc);
      #pragma unroll
      for (int d=0; d<64; ++d) acc = fmaf(__shfl(x1, d, 64), b2f(W[(d+64)*64+l]), acc);
    }
    const float stv = fmaxf(acc, 0.0f);

    float w0 = 0.f, w1 = 0.f;
    if (isf32){
      const float* W = (const float*)gat_W;
      #pragma unroll
      for (int d=0; d<64; ++d){
        const float sd = __shfl(stv, d, 64);
        w0 = fmaf(sd, W[d*128+l],    w0);
        w1 = fmaf(sd, W[d*128+64+l], w1);
      }
    } else {
      const bf16_t* W = (const bf16_t*)gat_W;
      #pragma unroll
      for (int d=0; d<64; ++d){
        const float sd = __shfl(stv, d, 64);
        w0 = fmaf(sd, b2f(W[d*128+l]),    w0);
        w1 = fmaf(sd, b2f(W[d*128+64+l]), w1);
      }
    }

    const size_t pbase = (size_t)(row >> 3)*1024 + (row & 7);
    Whb_p[pbase + (size_t)l*8]      = f2b(w0);
    Whb_p[pbase + (size_t)(l+64)*8] = f2b(w1);

    float a10, a11, a20, a21;
    if (isf32){
      const float* A = (const float*)gat_a;
      a10 = A[l]; a11 = A[l+64]; a20 = A[128+l]; a21 = A[192+l];
    } else {
      const bf16_t* A = (const bf16_t*)gat_a;
      a10 = b2f(A[l]); a11 = b2f(A[l+64]); a20 = b2f(A[128+l]); a21 = b2f(A[192+l]);
    }
    float r1 = w0*a10 + w1*a11;
    float r2 = w0*a20 + w1*a21;
    #pragma unroll
    for (int s=1; s<64; s<<=1){ r1 += __shfl_xor(r1, s, 64); r2 += __shfl_xor(r2, s, 64); }
    if (l == 0){ s1[row] = r1; s2[row] = r2; }
  }

  // ---- mask pack rotation: pack c, issue c+2 -------------------------------
  if (isf32){
    // pack chunk 0, issue chunk 2
    mrow[(0*4+0)*64 + l] = packf(vA0, vB0);
    mrow[(0*4+1)*64 + l] = packf(vA1, vB1);
    mrow[(0*4+2)*64 + l] = packf(vA2, vB2);
    mrow[(0*4+3)*64 + l] = packf(vA3, vB3);
    vA0 = a4[(size_t)((2*4+0)*64 + l)*2]; vB0 = a4[(size_t)((2*4+0)*64 + l)*2 + 1];
    vA1 = a4[(size_t)((2*4+1)*64 + l)*2]; vB1 = a4[(size_t)((2*4+1)*64 + l)*2 + 1];
    vA2 = a4[(size_t)((2*4+2)*64 + l)*2]; vB2 = a4[(size_t)((2*4+2)*64 + l)*2 + 1];
    vA3 = a4[(size_t)((2*4+3)*64 + l)*2]; vB3 = a4[(size_t)((2*4+3)*64 + l)*2 + 1];
    // pack chunk 1, issue chunk 3
    mrow[(1*4+0)*64 + l] = packf(wA0, wB0);
    mrow[(1*4+1)*64 + l] = packf(wA1, wB1);
    mrow[(1*4+2)*64 + l] = packf(wA2, wB2);
    mrow[(1*4+3)*64 + l] = packf(wA3, wB3);
    wA0 = a4[(size_t)((3*4+0)*64 + l)*2]; wB0 = a4[(size_t)((3*4+0)*64 + l)*2 + 1];
    wA1 = a4[(size_t)((3*4+1)*64 + l)*2]; wB1 = a4[(size_t)((3*4+1)*64 + l)*2 + 1];
    wA2 = a4[(size_t)((3*4+2)*64 + l)*2]; wB2 = a4[(size_t)((3*4+2)*64 + l)*2 + 1];
    wA3 = a4[(size_t)((3*4+3)*64 + l)*2]; wB3 = a4[(size_t)((3*4+3)*64 + l)*2 + 1];
    // pack chunks 2, 3
    mrow[(2*4+0)*64 + l] = packf(vA0, vB0);
    mrow[(2*4+1)*64 + l] = packf(vA1, vB1);
    mrow[(2*4+2)*64 + l] = packf(vA2, vB2);
    mrow[(2*4+3)*64 + l] = packf(vA3, vB3);
    mrow[(3*4+0)*64 + l] = packf(wA0, wB0);
    mrow[(3*4+1)*64 + l] = packf(wA1, wB1);
    mrow[(3*4+2)*64 + l] = packf(wA2, wB2);
    mrow[(3*4+3)*64 + l] = packf(wA3, wB3);
  } else {
    mrow[(0*4+0)*64 + l] = packb(q0);
    mrow[(0*4+1)*64 + l] = packb(q1);
    mrow[(0*4+2)*64 + l] = packb(q2);
    mrow[(0*4+3)*64 + l] = packb(q3);
    q0 = *(const bf16x8*)(a2 + (size_t)((2*4+0)*64 + l)*8);
    q1 = *(const bf16x8*)(a2 + (size_t)((2*4+1)*64 + l)*8);
    q2 = *(const bf16x8*)(a2 + (size_t)((2*4+2)*64 + l)*8);
    q3 = *(const bf16x8*)(a2 + (size_t)((2*4+3)*64 + l)*8);
    mrow[(1*4+0)*64 + l] = packb(p0);
    mrow[(1*4+1)*64 + l] = packb(p1);
    mrow[(1*4+2)*64 + l] = packb(p2);
    mrow[(1*4+3)*64 + l] = packb(p3);
    p0 = *(const bf16x8*)(a2 + (size_t)((3*4+0)*64 + l)*8);
    p1 = *(const bf16x8*)(a2 + (size_t)((3*4+1)*64 + l)*8);
    p2 = *(const bf16x8*)(a2 + (size_t)((3*4+2)*64 + l)*8);
    p3 = *(const bf16x8*)(a2 + (size_t)((3*4+3)*64 + l)*8);
    mrow[(2*4+0)*64 + l] = packb(q0);
    mrow[(2*4+1)*64 + l] = packb(q1);
    mrow[(2*4+2)*64 + l] = packb(q2);
    mrow[(2*4+3)*64 + l] = packb(q3);
    mrow[(3*4+0)*64 + l] = packb(p0);
    mrow[(3*4+1)*64 + l] = packb(p1);
    mrow[(3*4+2)*64 + l] = packb(p2);
    mrow[(3*4+3)*64 + l] = packb(p3);
  }
}

// ---------------------------------------------------------------------------
// K4: encoder LSTM via MFMA. gates = xb @ encWb^T (M=8192,N=256,K=128).
// ---------------------------------------------------------------------------
__global__ __launch_bounds__(256) void k_enc2(
    const unsigned short* __restrict__ xb, const unsigned short* __restrict__ Wb,
    const void* __restrict__ b_ih, const void* __restrict__ b_hh,
    const int* __restrict__ flag, unsigned short* __restrict__ h_enc_b)
{
  __shared__ float g_lds[32][257];
  const int tid = threadIdx.x, lane = tid & 63, wv = tid >> 6;
  const int quad = lane >> 4, nn = lane & 15;
  const int rowbase = blockIdx.x * 32;
  const int rows_off = (wv & 1) * 16;
  const int col_off  = (wv >> 1) * 128;

  f32x4 acc[8];
  #pragma unroll
  for (int t=0;t<8;++t) acc[t] = (f32x4){0.f,0.f,0.f,0.f};

  #pragma unroll
  for (int ks=0; ks<4; ++ks){
    const int kb = ks*32 + quad*8;
    bf16x8 afrag = *(const bf16x8*)(xb + (size_t)(rowbase + rows_off + nn)*128 + kb);
    #pragma unroll
    for (int t=0;t<8;++t){
      bf16x8 bfrag = *(const bf16x8*)(Wb + (size_t)(col_off + t*16 + nn)*128 + kb);
      acc[t] = __builtin_amdgcn_mfma_f32_16x16x32_bf16(afrag, bfrag, acc[t], 0, 0, 0);
    }
  }
  #pragma unroll
  for (int t=0;t<8;++t)
    #pragma unroll
    for (int r=0;r<4;++r)
      g_lds[rows_off + quad*4 + r][col_off + t*16 + nn] = acc[t][r];
  __syncthreads();

  const int isf32 = flag[0];
  #pragma unroll
  for (int k=0;k<8;++k){
    const int idx = tid + k*256;          // 32 rows x 64 hid
    const int r = idx >> 6, hid = idx & 63;
    float bi, bg, bo;
    if (isf32){
      const float* bi1 = (const float*)b_ih; const float* bi2 = (const float*)b_hh;
      bi = bi1[hid]     + bi2[hid];
      bg = bi1[128+hid] + bi2[128+hid];
      bo = bi1[192+hid] + bi2[192+hid];
    } else {
      const bf16_t* bi1 = (const bf16_t*)b_ih; const bf16_t* bi2 = (const bf16_t*)b_hh;
      bi = b2f(bi1[hid])     + b2f(bi2[hid]);
      bg = b2f(bi1[128+hid]) + b2f(bi2[128+hid]);
      bo = b2f(bi1[192+hid]) + b2f(bi2[192+hid]);
    }
    const float gi = g_lds[r][hid]     + bi;
    const float gg = g_lds[r][128+hid] + bg;
    const float go = g_lds[r][192+hid] + bo;
    const float c = tanhf(gg) * sigf(gi);
    const float h = tanhf(c)  * sigf(go);
    h_enc_b[(size_t)(rowbase + r)*64 + hid] = f2b(h);
  }
}

// ---------------------------------------------------------------------------
// K5: decoder LSTM via MFMA. gates = h_enc_b @ decWb^T (M=8192,N=512,K=64).
// ---------------------------------------------------------------------------
__global__ __launch_bounds__(256) void k_dec2(
    const unsigned short* __restrict__ hb, const unsigned short* __restrict__ Wb,
    const void* __restrict__ b_ih, const void* __restrict__ b_hh,
    const int* __restrict__ flag, void* __restrict__ d_out)
{
  __shared__ float g_lds[16][517];
  const int tid = threadIdx.x, lane = tid & 63, wv = tid >> 6;
  const int quad = lane >> 4, nn = lane & 15;
  const int rowbase = blockIdx.x * 16;
  const int col_off = wv * 128;

  f32x4 acc[8];
  #pragma unroll
  for (int t=0;t<8;++t) acc[t] = (f32x4){0.f,0.f,0.f,0.f};

  #pragma unroll
  for (int ks=0; ks<2; ++ks){
    const int kb = ks*32 + quad*8;
    bf16x8 afrag = *(const bf16x8*)(hb + (size_t)(rowbase + nn)*64 + kb);
    #pragma unroll
    for (int t=0;t<8;++t){
      bf16x8 bfrag = *(const bf16x8*)(Wb + (size_t)(col_off + t*16 + nn)*64 + kb);
      acc[t] = __builtin_amdgcn_mfma_f32_16x16x32_bf16(afrag, bfrag, acc[t], 0, 0, 0);
    }
  }
  #pragma unroll
  for (int t=0;t<8;++t)
    #pragma unroll
    for (int r=0;r<4;++r)
      g_lds[quad*4 + r][col_off + t*16 + nn] = acc[t][r];
  __syncthreads();

  const int isf32 = flag[0];
  #pragma unroll
  for (int k=0;k<8;++k){
    const int idx = tid + k*256;          // 16 rows x 128 cols
    const int r = idx >> 7, col = idx & 127;
    float bi, bg, bo;
    if (isf32){
      const float* b1 = (const float*)b_ih; const float* b2 = (const float*)b_hh;
      bi = b1[col]     + b2[col];
      bg = b1[256+col] + b2[256+col];
      bo = b1[384+col] + b2[384+col];
    } else {
      const bf16_t* b1 = (const bf16_t*)b_ih; const bf16_t* b2v = (const bf16_t*)b_hh;
      bi = b2f(b1[col])     + b2f(b2v[col]);
      bg = b2f(b1[256+col]) + b2f(b2v[256+col]);
      bo = b2f(b1[384+col]) + b2f(b2v[384+col]);
    }
    const float gi = g_lds[r][col]     + bi;
    const float gg = g_lds[r][256+col] + bg;
    const float go = g_lds[r][384+col] + bo;
    const float c = tanhf(gg) * sigf(gi);
    const float h = tanhf(c)  * sigf(go);
    const size_t oidx = (size_t)NROW*NROW + (size_t)(rowbase + r)*128 + col;
    if (isf32) ((float*)d_out)[oidx] = h;
    else       ((unsigned short*)d_out)[oidx] = f2b(h);
  }
}

// ---------------------------------------------------------------------------
// K6: attention — j-SPLIT: 512 blocks = 256 row-tiles (32 rows) x 2 j-halves.
// Writes f32 partial C + partial denominators; k_merge finishes.
// ---------------------------------------------------------------------------
__global__ __launch_bounds__(512) void k_attn32s(
    const unsigned char* __restrict__ mask8, const unsigned short* __restrict__ Whb_p,
    const float* __restrict__ s1g, const float* __restrict__ s2g,
    float* __restrict__ Cpart, float* __restrict__ dnpart)
{
  __shared__ float C_lds[8][16*128];
  __shared__ float dn_lds[8][32];
  const int tid  = threadIdx.x;
  const int lane = tid & 63;
  const int wv   = tid >> 6;
  const int quad = lane >> 4;
  const int mrow = lane & 15;
  const int rowtile = blockIdx.x & 255;
  const int half    = blockIdx.x >> 8;
  const int rowbase = rowtile * 32;
  const float s1r0 = s1g[rowbase + mrow];
  const float s1r1 = s1g[rowbase + 16 + mrow];
  const unsigned char* mp0 = mask8 + (size_t)(rowbase + mrow) * 1024;
  const unsigned char* mp1 = mask8 + (size_t)(rowbase + 16 + mrow) * 1024;

  f32x4 acc[2][8];
  #pragma unroll
  for (int g=0;g<2;++g)
    #pragma unroll
    for (int t=0;t<8;++t) acc[g][t] = (f32x4){0.f,0.f,0.f,0.f};
  float dn0 = 0.f, dn1 = 0.f;

  const int jbeg = half*4096 + wv*512;
  for (int j0 = jbeg; j0 < jbeg + 512; j0 += 128){
    uint4 mw0 = *(const uint4*)(mp0 + (j0 >> 3));
    uint4 mw1 = *(const uint4*)(mp1 + (j0 >> 3));
    #pragma unroll
    for (int t4=0; t4<4; ++t4){
      const unsigned int mb0 = ((((const unsigned int*)&mw0)[t4]) >> (8*quad)) & 0xffu;
      const unsigned int mb1 = ((((const unsigned int*)&mw1)[t4]) >> (8*quad)) & 0xffu;
      const int kb = j0 + t4*32 + quad*8;
      float4 s2a = *(const float4*)(s2g + kb);
      float4 s2b = *(const float4*)(s2g + kb + 4);
      const float sv[8] = { s2a.x, s2a.y, s2a.z, s2a.w, s2b.x, s2b.y, s2b.z, s2b.w };
      bf16x8 af0, af1;
      #pragma unroll
      for (int b=0;b<8;++b){
        float v0 = s1r0 + sv[b];
        v0 = (v0 > 0.f) ? v0 : LEAKY * v0;
        const float e0 = __expf(v0);
        const float p0 = (mb0 & (1u<<b)) ? e0 : 0.f;
        dn0 += p0;
        af0[b] = (short)f2b(p0);
        float v1 = s1r1 + sv[b];
        v1 = (v1 > 0.f) ? v1 : LEAKY * v1;
        const float e1 = __expf(v1);
        const float p1 = (mb1 & (1u<<b)) ? e1 : 0.f;
        dn1 += p1;
        af1[b] = (short)f2b(p1);
      }
      const unsigned short* wb = Whb_p + (size_t)(kb >> 3)*1024 + mrow*8;
      #pragma unroll
      for (int t=0;t<8;++t){
        bf16x8 bfrag = *(const bf16x8*)(wb + t*128);
        acc[0][t] = __builtin_amdgcn_mfma_f32_16x16x32_bf16(af0, bfrag, acc[0][t], 0, 0, 0);
        acc[1][t] = __builtin_amdgcn_mfma_f32_16x16x32_bf16(af1, bfrag, acc[1][t], 0, 0, 0);
      }
    }
  }

  dn0 += __shfl_xor(dn0, 16, 64);
  dn0 += __shfl_xor(dn0, 32, 64);
  dn1 += __shfl_xor(dn1, 16, 64);
  dn1 += __shfl_xor(dn1, 32, 64);
  if (lane < 16){ dn_lds[wv][lane] = dn0; dn_lds[wv][16 + lane] = dn1; }

  float* Ch = Cpart + (size_t)half * NROW * 128;
  #pragma unroll
  for (int rg=0; rg<2; ++rg){
    #pragma unroll
    for (int t=0;t<8;++t){
      #pragma unroll
      for (int r=0;r<4;++r)
        C_lds[wv][(quad*4+r)*128 + t*16 + mrow] = acc[rg][t][r];
    }
    __syncthreads();
    for (int idx = tid; idx < 16*128; idx += 512){
      const int m = idx >> 7;
      const int d = idx & 127;
      const float v = C_lds[0][idx] + C_lds[1][idx] + C_lds[2][idx] + C_lds[3][idx]
                    + C_lds[4][idx] + C_lds[5][idx] + C_lds[6][idx] + C_lds[7][idx];
      Ch[(size_t)(rowbase + rg*16 + m)*128 + d] = v;
      if (d == 0){
        const float den = dn_lds[0][rg*16+m] + dn_lds[1][rg*16+m] + dn_lds[2][rg*16+m]
                        + dn_lds[3][rg*16+m] + dn_lds[4][rg*16+m] + dn_lds[5][rg*16+m]
                        + dn_lds[6][rg*16+m] + dn_lds[7][rg*16+m];
        dnpart[half*NROW + rowbase + rg*16 + m] = den;
      }
    }
    __syncthreads();
  }
}

// ---------------------------------------------------------------------------
// K6b: merge halves: emb = elu( (C0+C1) / (dn0+dn1) ), k-packed bf16 out.
// ---------------------------------------------------------------------------
__global__ __launch_bounds__(256) void k_merge(
    const float* __restrict__ Cpart, const float* __restrict__ dnpart,
    unsigned short* __restrict__ emb_p)
{
  const int tid = threadIdx.x;
  const int rowbase = blockIdx.x * 16;
  const float* C0 = Cpart;
  const float* C1 = Cpart + (size_t)NROW * 128;
  #pragma unroll
  for (int k=0;k<8;++k){
    const int idx = tid + k*256;       // 16 rows x 128 d
    const int m = idx >> 7;
    const int d = idx & 127;
    const int row = rowbase + m;
    const float den = dnpart[row] + dnpart[NROW + row];
    float v = (C0[(size_t)row*128 + d] + C1[(size_t)row*128 + d]) / den;
    v = (v > 0.f) ? v : (__expf(v) - 1.f);   // elu
    emb_p[(size_t)(d >> 3)*65536 + (size_t)row*8 + (d & 7)] = f2b(v);
  }
}

// ---------------------------------------------------------------------------
// K7: con_adj = emb @ emb^T. emb_p k-packed: (k>>3)*65536 + row*8 + (k&7).
// ---------------------------------------------------------------------------
__global__ __launch_bounds__(256) void k_out(
    const unsigned short* __restrict__ emb_p, const int* __restrict__ flag,
    void* __restrict__ d_out)
{
  const int tid  = threadIdx.x;
  const int lane = tid & 63, wv = tid >> 6;
  const int quad = lane >> 4, nn = lane & 15;
  const int i0 = blockIdx.y * 128 + wv * 32;
  const int j0 = blockIdx.x * 64;

  f32x4 acc[2][4];
  #pragma unroll
  for (int a=0;a<2;++a)
    #pragma unroll
    for (int b=0;b<4;++b) acc[a][b] = (f32x4){0.f,0.f,0.f,0.f};

  #pragma unroll
  for (int ks=0; ks<4; ++ks){
    const int kb = ks*32 + quad*8;
    const unsigned short* base = emb_p + (size_t)(kb >> 3)*65536;
    bf16x8 a0 = *(const bf16x8*)(base + (size_t)(i0 + nn)*8);
    bf16x8 a1 = *(const bf16x8*)(base + (size_t)(i0 + 16 + nn)*8);
    #pragma unroll
    for (int t=0;t<4;++t){
      bf16x8 b = *(const bf16x8*)(base + (size_t)(j0 + t*16 + nn)*8);
      acc[0][t] = __builtin_amdgcn_mfma_f32_16x16x32_bf16(a0, b, acc[0][t], 0, 0, 0);
      acc[1][t] = __builtin_amdgcn_mfma_f32_16x16x32_bf16(a1, b, acc[1][t], 0, 0, 0);
    }
  }

  const int isf32 = flag[0];
  if (isf32){
    float* out = (float*)d_out;
    #pragma unroll
    for (int mi=0; mi<2; ++mi)
      #pragma unroll
      for (int t=0;t<4;++t)
        #pragma unroll
        for (int r=0;r<4;++r)
          out[(size_t)(i0 + mi*16 + quad*4 + r)*NROW + j0 + t*16 + nn] = acc[mi][t][r];
  } else {
    unsigned short* out = (unsigned short*)d_out;
    #pragma unroll
    for (int mi=0; mi<2; ++mi)
      #pragma unroll
      for (int t=0;t<4;++t)
        #pragma unroll
        for (int r=0;r<4;++r)
          out[(size_t)(i0 + mi*16 + quad*4 + r)*NROW + j0 + t*16 + nn] = f2b(acc[mi][t][r]);
  }
}

// ---------------------------------------------------------------------------
extern "C" void kernel_launch(void* const* d_in, const int* in_sizes, int n_in,
                              void* d_out, int out_size, void* d_ws, size_t ws_size,
                              hipStream_t stream)
{
  (void)in_sizes; (void)n_in; (void)out_size; (void)ws_size;
  const void* x        = d_in[0];
  const void* adj      = d_in[1];
  const void* fea_W    = d_in[2];
  const void* fea_b    = d_in[3];
  const void* gat_W    = d_in[4];
  const void* gat_a    = d_in[5];
  const void* enc_W_ih = d_in[6];
  const void* enc_b_ih = d_in[8];
  const void* enc_b_hh = d_in[9];
  const void* dec_W_ih = d_in[10];
  const void* dec_b_ih = d_in[12];
  const void* dec_b_hh = d_in[13];

  char* ws = (char*)d_ws;
  unsigned short* Whb_p   = (unsigned short*)ws;                 // 2 MB  Wh k-packed bf16
  unsigned short* emb_p   = (unsigned short*)(ws + (2u<<20));    // 2 MB  emb k-packed bf16
  unsigned short* xb      = (unsigned short*)(ws + (4u<<20));    // 2 MB  x bf16
  unsigned short* h_enc_b = (unsigned short*)(ws + (6u<<20));    // 1 MB  h_enc bf16
  unsigned char*  mask8   = (unsigned char*) (ws + (7u<<20));    // 8 MB  adj bitmask
  float* s1    = (float*)(ws + (15u<<20));                       // 32 KB
  float* s2    = (float*)(ws + (15u<<20) + 32768);               // 32 KB
  unsigned short* encWb = (unsigned short*)(ws + (15u<<20) + 65536);          // 64 KB
  unsigned short* decWb = (unsigned short*)(ws + (15u<<20) + 65536 + 65536);  // 64 KB
  int* flag = (int*)(ws + (15u<<20) + 3*65536);
  float* Cpart  = (float*)(ws + (16u<<20));                      // 8 MB  partial C (2 halves)
  float* dnpart = (float*)(ws + (24u<<20));                      // 64 KB partial denominators

  k_probe<<<1, 64, 0, stream>>>((const unsigned short*)x, flag);
  k_cvt<<<256, 256, 0, stream>>>(enc_W_ih, dec_W_ih, flag, encWb, decWb);
  k_feamask4<<<2048, 256, 0, stream>>>(x, adj, fea_W, fea_b, gat_W, gat_a, flag,
                                       Whb_p, s1, s2, xb, mask8);
  k_enc2<<<256, 256, 0, stream>>>(xb, encWb, enc_b_ih, enc_b_hh, flag, h_enc_b);
  k_dec2<<<512, 256, 0, stream>>>(h_enc_b, decWb, dec_b_ih, dec_b_hh, flag, d_out);
  k_attn32s<<<512, 512, 0, stream>>>(mask8, Whb_p, s1, s2, Cpart, dnpart);
  k_merge<<<512, 256, 0, stream>>>(Cpart, dnpart, emb_p);
  k_out<<<dim3(128, 64), 256, 0, stream>>>(emb_p, flag, d_out);
}

// Round 10
// 566.229 us; speedup vs baseline: 1.1627x; 1.1627x over previous
//
#include <hip/hip_runtime.h>
#include <hip/hip_bf16.h>

typedef __hip_bfloat16 bf16_t;
typedef short bf16x8 __attribute__((ext_vector_type(8)));
typedef float f32x4 __attribute__((ext_vector_type(4)));

#define NROW 8192
#define LEAKY 0.2f

__device__ __forceinline__ float b2f(bf16_t v){ return __bfloat162float(v); }
__device__ __forceinline__ unsigned short f2b(float f){
  union { bf16_t h; unsigned short u; } cv; cv.h = __float2bfloat16(f); return cv.u;
}
__device__ __forceinline__ float sigf(float v){ return 1.0f / (1.0f + __expf(-v)); }

// ---------------------------------------------------------------------------
// K0: dtype probe. flag[0] = 1 if inputs are float32, 0 if bf16.
// ---------------------------------------------------------------------------
__global__ void k_probe(const unsigned short* __restrict__ x_raw, int* __restrict__ flag)
{
  const int lane = threadIdx.x;
  int cnt = 0;
  for (int k = lane; k < 512; k += 64){
    const int e = (x_raw[k] >> 7) & 0xff;
    cnt += (e >= 120 && e <= 130) ? 1 : 0;
  }
  #pragma unroll
  for (int s = 1; s < 64; s <<= 1) cnt += __shfl_xor(cnt, s, 64);
  if (lane == 0) flag[0] = (cnt < 384) ? 1 : 0;
}

// ---------------------------------------------------------------------------
// K1: weight converts to bf16: enc_W_ih (256x128), dec_W_ih (512x64).
// ---------------------------------------------------------------------------
__global__ __launch_bounds__(256) void k_cvt(
    const void* __restrict__ encW, const void* __restrict__ decW,
    const int* __restrict__ flag,
    unsigned short* __restrict__ encWb, unsigned short* __restrict__ decWb)
{
  const int idx = blockIdx.x*256 + threadIdx.x;
  const int isf32 = flag[0];
  if (idx < 32768){
    float v = isf32 ? ((const float*)encW)[idx] : b2f(((const bf16_t*)encW)[idx]);
    encWb[idx] = f2b(v);
  } else {
    const int j = idx - 32768;
    float v = isf32 ? ((const float*)decW)[j] : b2f(((const bf16_t*)decW)[j]);
    decWb[j] = f2b(v);
  }
}

// ---------------------------------------------------------------------------
// K2 (R1 proven body + XCD-AWARE ROW SWIZZLE): fused fea+mask, barrier-free.
// row = (bid&7)*1024 + (bid>>3): with round-robin block->XCD dispatch, each
// XCD processes a CONTIGUOUS 1024-row (32 MB, 8K-page) slice of adj ->
// 8x fewer page walks per XCD + XCD-L2 locality for the L3-resident half.
// ---------------------------------------------------------------------------
__global__ __launch_bounds__(256) void k_feamask(
    const void* __restrict__ x, const void* __restrict__ adj,
    const void* __restrict__ fea_W, const void* __restrict__ fea_b,
    const void* __restrict__ gat_W, const void* __restrict__ gat_a,
    const int* __restrict__ flag,
    unsigned short* __restrict__ Whb_p, float* __restrict__ s1, float* __restrict__ s2,
    unsigned short* __restrict__ xb, unsigned char* __restrict__ mask8)
{
  const int bid = blockIdx.x;
  const int r   = (bid & 7) * 1024 + (bid >> 3);   // XCD-contiguous row slice
  const int tid = threadIdx.x;
  const int isf32 = flag[0];

  // ---- adj loads issued early (kept in VGPRs; no barrier ever drains them) --
  float4 mv0, mv1, mv2, mv3, mv4, mv5, mv6, mv7;
  bf16x8 bv0, bv1, bv2, bv3;
  if (isf32){
    const float4* arow = (const float4*)((const float*)adj + (size_t)r*NROW);
    mv0 = arow[(size_t)tid*2];         mv1 = arow[(size_t)tid*2+1];
    mv2 = arow[(size_t)(tid+256)*2];   mv3 = arow[(size_t)(tid+256)*2+1];
    mv4 = arow[(size_t)(tid+512)*2];   mv5 = arow[(size_t)(tid+512)*2+1];
    mv6 = arow[(size_t)(tid+768)*2];   mv7 = arow[(size_t)(tid+768)*2+1];
  } else {
    const unsigned short* arow = (const unsigned short*)adj + (size_t)r*NROW;
    bv0 = *(const bf16x8*)(arow + (size_t)tid*8);
    bv1 = *(const bf16x8*)(arow + (size_t)(tid+256)*8);
    bv2 = *(const bf16x8*)(arow + (size_t)(tid+512)*8);
    bv3 = *(const bf16x8*)(arow + (size_t)(tid+768)*8);
  }

  // ---- fea: wave 0 only, barrier-free --------------------------------------
  if (tid < 64){
    const int l = tid;
    float x0, x1;
    if (isf32){
      const float* xr = (const float*)x + (size_t)r*128;
      x0 = xr[l]; x1 = xr[l+64];
    } else {
      const bf16_t* xr = (const bf16_t*)x + (size_t)r*128;
      x0 = b2f(xr[l]); x1 = b2f(xr[l+64]);
    }
    xb[(size_t)r*128 + l]      = f2b(x0);
    xb[(size_t)r*128 + 64 + l] = f2b(x1);

    float acc = isf32 ? ((const float*)fea_b)[l] : b2f(((const bf16_t*)fea_b)[l]);
    if (isf32){
      const float* W = (const float*)fea_W;
      #pragma unroll
      for (int d=0; d<64; ++d) acc = fmaf(__shfl(x0, d, 64), W[d*64+l], acc);
      #pragma unroll
      for (int d=0; d<64; ++d) acc = fmaf(__shfl(x1, d, 64), W[(d+64)*64+l], acc);
    } else {
      const bf16_t* W = (const bf16_t*)fea_W;
      #pragma unroll
      for (int d=0; d<64; ++d) acc = fmaf(__shfl(x0, d, 64), b2f(W[d*64+l]), acc);
      #pragma unroll
      for (int d=0; d<64; ++d) acc = fmaf(__shfl(x1, d, 64), b2f(W[(d+64)*64+l]), acc);
    }
    const float stv = fmaxf(acc, 0.0f);

    float w0 = 0.f, w1 = 0.f;
    if (isf32){
      const float* W = (const float*)gat_W;
      #pragma unroll
      for (int d=0; d<64; ++d){
        const float sd = __shfl(stv, d, 64);
        w0 = fmaf(sd, W[d*128+l],    w0);
        w1 = fmaf(sd, W[d*128+64+l], w1);
      }
    } else {
      const bf16_t* W = (const bf16_t*)gat_W;
      #pragma unroll
      for (int d=0; d<64; ++d){
        const float sd = __shfl(stv, d, 64);
        w0 = fmaf(sd, b2f(W[d*128+l]),    w0);
        w1 = fmaf(sd, b2f(W[d*128+64+l]), w1);
      }
    }

    const size_t pbase = (size_t)(r >> 3)*1024 + (r & 7);
    Whb_p[pbase + (size_t)l*8]      = f2b(w0);
    Whb_p[pbase + (size_t)(l+64)*8] = f2b(w1);

    float a10, a11, a20, a21;
    if (isf32){
      const float* A = (const float*)gat_a;
      a10 = A[l]; a11 = A[l+64]; a20 = A[128+l]; a21 = A[192+l];
    } else {
      const bf16_t* A = (const bf16_t*)gat_a;
      a10 = b2f(A[l]); a11 = b2f(A[l+64]); a20 = b2f(A[128+l]); a21 = b2f(A[192+l]);
    }
    float r1 = w0*a10 + w1*a11;
    float r2 = w0*a20 + w1*a21;
    #pragma unroll
    for (int s=1; s<64; s<<=1){ r1 += __shfl_xor(r1, s, 64); r2 += __shfl_xor(r2, s, 64); }
    if (l == 0){ s1[r] = r1; s2[r] = r2; }
  }

  // ---- mask pack & store ----------------------------------------------------
  if (isf32){
    const float4 va[8] = { mv0, mv1, mv2, mv3, mv4, mv5, mv6, mv7 };
    #pragma unroll
    for (int k=0;k<4;++k){
      const float4 v0 = va[2*k], v1 = va[2*k+1];
      unsigned int m =
          (unsigned int)(v0.x>0.f)      | ((unsigned int)(v0.y>0.f)<<1) |
          ((unsigned int)(v0.z>0.f)<<2) | ((unsigned int)(v0.w>0.f)<<3) |
          ((unsigned int)(v1.x>0.f)<<4) | ((unsigned int)(v1.y>0.f)<<5) |
          ((unsigned int)(v1.z>0.f)<<6) | ((unsigned int)(v1.w>0.f)<<7);
      mask8[(size_t)r*1024 + tid + k*256] = (unsigned char)m;
    }
  } else {
    const bf16x8 vb[4] = { bv0, bv1, bv2, bv3 };
    #pragma unroll
    for (int k=0;k<4;++k){
      unsigned int m = 0;
      #pragma unroll
      for (int j=0;j<8;++j){
        union { short s; unsigned short u; } cv; cv.s = vb[k][j];
        union { unsigned short u; bf16_t h; } cv2; cv2.u = cv.u;
        m |= ((unsigned int)(b2f(cv2.h) > 0.f)) << j;
      }
      mask8[(size_t)r*1024 + tid + k*256] = (unsigned char)m;
    }
  }
}

// ---------------------------------------------------------------------------
// K4: encoder LSTM via MFMA. gates = xb @ encWb^T (M=8192,N=256,K=128).
// ---------------------------------------------------------------------------
__global__ __launch_bounds__(256) void k_enc2(
    const unsigned short* __restrict__ xb, const unsigned short* __restrict__ Wb,
    const void* __restrict__ b_ih, const void* __restrict__ b_hh,
    const int* __restrict__ flag, unsigned short* __restrict__ h_enc_b)
{
  __shared__ float g_lds[32][257];
  const int tid = threadIdx.x, lane = tid & 63, wv = tid >> 6;
  const int quad = lane >> 4, nn = lane & 15;
  const int rowbase = blockIdx.x * 32;
  const int rows_off = (wv & 1) * 16;
  const int col_off  = (wv >> 1) * 128;

  f32x4 acc[8];
  #pragma unroll
  for (int t=0;t<8;++t) acc[t] = (f32x4){0.f,0.f,0.f,0.f};

  #pragma unroll
  for (int ks=0; ks<4; ++ks){
    const int kb = ks*32 + quad*8;
    bf16x8 afrag = *(const bf16x8*)(xb + (size_t)(rowbase + rows_off + nn)*128 + kb);
    #pragma unroll
    for (int t=0;t<8;++t){
      bf16x8 bfrag = *(const bf16x8*)(Wb + (size_t)(col_off + t*16 + nn)*128 + kb);
      acc[t] = __builtin_amdgcn_mfma_f32_16x16x32_bf16(afrag, bfrag, acc[t], 0, 0, 0);
    }
  }
  #pragma unroll
  for (int t=0;t<8;++t)
    #pragma unroll
    for (int r=0;r<4;++r)
      g_lds[rows_off + quad*4 + r][col_off + t*16 + nn] = acc[t][r];
  __syncthreads();

  const int isf32 = flag[0];
  #pragma unroll
  for (int k=0;k<8;++k){
    const int idx = tid + k*256;          // 32 rows x 64 hid
    const int r = idx >> 6, hid = idx & 63;
    float bi, bg, bo;
    if (isf32){
      const float* bi1 = (const float*)b_ih; const float* bi2 = (const float*)b_hh;
      bi = bi1[hid]     + bi2[hid];
      bg = bi1[128+hid] + bi2[128+hid];
      bo = bi1[192+hid] + bi2[192+hid];
    } else {
      const bf16_t* bi1 = (const bf16_t*)b_ih; const bf16_t* bi2 = (const bf16_t*)b_hh;
      bi = b2f(bi1[hid])     + b2f(bi2[hid]);
      bg = b2f(bi1[128+hid]) + b2f(bi2[128+hid]);
      bo = b2f(bi1[192+hid]) + b2f(bi2[192+hid]);
    }
    const float gi = g_lds[r][hid]     + bi;
    const float gg = g_lds[r][128+hid] + bg;
    const float go = g_lds[r][192+hid] + bo;
    const float c = tanhf(gg) * sigf(gi);
    const float h = tanhf(c)  * sigf(go);
    h_enc_b[(size_t)(rowbase + r)*64 + hid] = f2b(h);
  }
}

// ---------------------------------------------------------------------------
// K5: decoder LSTM via MFMA. gates = h_enc_b @ decWb^T (M=8192,N=512,K=64).
// ---------------------------------------------------------------------------
__global__ __launch_bounds__(256) void k_dec2(
    const unsigned short* __restrict__ hb, const unsigned short* __restrict__ Wb,
    const void* __restrict__ b_ih, const void* __restrict__ b_hh,
    const int* __restrict__ flag, void* __restrict__ d_out)
{
  __shared__ float g_lds[16][517];
  const int tid = threadIdx.x, lane = tid & 63, wv = tid >> 6;
  const int quad = lane >> 4, nn = lane & 15;
  const int rowbase = blockIdx.x * 16;
  const int col_off = wv * 128;

  f32x4 acc[8];
  #pragma unroll
  for (int t=0;t<8;++t) acc[t] = (f32x4){0.f,0.f,0.f,0.f};

  #pragma unroll
  for (int ks=0; ks<2; ++ks){
    const int kb = ks*32 + quad*8;
    bf16x8 afrag = *(const bf16x8*)(hb + (size_t)(rowbase + nn)*64 + kb);
    #pragma unroll
    for (int t=0;t<8;++t){
      bf16x8 bfrag = *(const bf16x8*)(Wb + (size_t)(col_off + t*16 + nn)*64 + kb);
      acc[t] = __builtin_amdgcn_mfma_f32_16x16x32_bf16(afrag, bfrag, acc[t], 0, 0, 0);
    }
  }
  #pragma unroll
  for (int t=0;t<8;++t)
    #pragma unroll
    for (int r=0;r<4;++r)
      g_lds[quad*4 + r][col_off + t*16 + nn] = acc[t][r];
  __syncthreads();

  const int isf32 = flag[0];
  #pragma unroll
  for (int k=0;k<8;++k){
    const int idx = tid + k*256;          // 16 rows x 128 cols
    const int r = idx >> 7, col = idx & 127;
    float bi, bg, bo;
    if (isf32){
      const float* b1 = (const float*)b_ih; const float* b2 = (const float*)b_hh;
      bi = b1[col]     + b2[col];
      bg = b1[256+col] + b2[256+col];
      bo = b1[384+col] + b2[384+col];
    } else {
      const bf16_t* b1 = (const bf16_t*)b_ih; const bf16_t* b2v = (const bf16_t*)b_hh;
      bi = b2f(b1[col])     + b2f(b2v[col]);
      bg = b2f(b1[256+col]) + b2f(b2v[256+col]);
      bo = b2f(b1[384+col]) + b2f(b2v[384+col]);
    }
    const float gi = g_lds[r][col]     + bi;
    const float gg = g_lds[r][256+col] + bg;
    const float go = g_lds[r][384+col] + bo;
    const float c = tanhf(gg) * sigf(gi);
    const float h = tanhf(c)  * sigf(go);
    const size_t oidx = (size_t)NROW*NROW + (size_t)(rowbase + r)*128 + col;
    if (isf32) ((float*)d_out)[oidx] = h;
    else       ((unsigned short*)d_out)[oidx] = f2b(h);
  }
}

// ---------------------------------------------------------------------------
// K6: attention — j-SPLIT: 512 blocks = 256 row-tiles (32 rows) x 2 j-halves.
// Writes f32 partial C + partial denominators; k_merge finishes.
// ---------------------------------------------------------------------------
__global__ __launch_bounds__(512) void k_attn32s(
    const unsigned char* __restrict__ mask8, const unsigned short* __restrict__ Whb_p,
    const float* __restrict__ s1g, const float* __restrict__ s2g,
    float* __restrict__ Cpart, float* __restrict__ dnpart)
{
  __shared__ float C_lds[8][16*128];
  __shared__ float dn_lds[8][32];
  const int tid  = threadIdx.x;
  const int lane = tid & 63;
  const int wv   = tid >> 6;
  const int quad = lane >> 4;
  const int mrow = lane & 15;
  const int rowtile = blockIdx.x & 255;
  const int half    = blockIdx.x >> 8;
  const int rowbase = rowtile * 32;
  const float s1r0 = s1g[rowbase + mrow];
  const float s1r1 = s1g[rowbase + 16 + mrow];
  const unsigned char* mp0 = mask8 + (size_t)(rowbase + mrow) * 1024;
  const unsigned char* mp1 = mask8 + (size_t)(rowbase + 16 + mrow) * 1024;

  f32x4 acc[2][8];
  #pragma unroll
  for (int g=0;g<2;++g)
    #pragma unroll
    for (int t=0;t<8;++t) acc[g][t] = (f32x4){0.f,0.f,0.f,0.f};
  float dn0 = 0.f, dn1 = 0.f;

  const int jbeg = half*4096 + wv*512;
  for (int j0 = jbeg; j0 < jbeg + 512; j0 += 128){
    uint4 mw0 = *(const uint4*)(mp0 + (j0 >> 3));
    uint4 mw1 = *(const uint4*)(mp1 + (j0 >> 3));
    #pragma unroll
    for (int t4=0; t4<4; ++t4){
      const unsigned int mb0 = ((((const unsigned int*)&mw0)[t4]) >> (8*quad)) & 0xffu;
      const unsigned int mb1 = ((((const unsigned int*)&mw1)[t4]) >> (8*quad)) & 0xffu;
      const int kb = j0 + t4*32 + quad*8;
      float4 s2a = *(const float4*)(s2g + kb);
      float4 s2b = *(const float4*)(s2g + kb + 4);
      const float sv[8] = { s2a.x, s2a.y, s2a.z, s2a.w, s2b.x, s2b.y, s2b.z, s2b.w };
      bf16x8 af0, af1;
      #pragma unroll
      for (int b=0;b<8;++b){
        float v0 = s1r0 + sv[b];
        v0 = (v0 > 0.f) ? v0 : LEAKY * v0;
        const float e0 = __expf(v0);
        const float p0 = (mb0 & (1u<<b)) ? e0 : 0.f;
        dn0 += p0;
        af0[b] = (short)f2b(p0);
        float v1 = s1r1 + sv[b];
        v1 = (v1 > 0.f) ? v1 : LEAKY * v1;
        const float e1 = __expf(v1);
        const float p1 = (mb1 & (1u<<b)) ? e1 : 0.f;
        dn1 += p1;
        af1[b] = (short)f2b(p1);
      }
      const unsigned short* wb = Whb_p + (size_t)(kb >> 3)*1024 + mrow*8;
      #pragma unroll
      for (int t=0;t<8;++t){
        bf16x8 bfrag = *(const bf16x8*)(wb + t*128);
        acc[0][t] = __builtin_amdgcn_mfma_f32_16x16x32_bf16(af0, bfrag, acc[0][t], 0, 0, 0);
        acc[1][t] = __builtin_amdgcn_mfma_f32_16x16x32_bf16(af1, bfrag, acc[1][t], 0, 0, 0);
      }
    }
  }

  dn0 += __shfl_xor(dn0, 16, 64);
  dn0 += __shfl_xor(dn0, 32, 64);
  dn1 += __shfl_xor(dn1, 16, 64);
  dn1 += __shfl_xor(dn1, 32, 64);
  if (lane < 16){ dn_lds[wv][lane] = dn0; dn_lds[wv][16 + lane] = dn1; }

  float* Ch = Cpart + (size_t)half * NROW * 128;
  #pragma unroll
  for (int rg=0; rg<2; ++rg){
    #pragma unroll
    for (int t=0;t<8;++t){
      #pragma unroll
      for (int r=0;r<4;++r)
        C_lds[wv][(quad*4+r)*128 + t*16 + mrow] = acc[rg][t][r];
    }
    __syncthreads();
    for (int idx = tid; idx < 16*128; idx += 512){
      const int m = idx >> 7;
      const int d = idx & 127;
      const float v = C_lds[0][idx] + C_lds[1][idx] + C_lds[2][idx] + C_lds[3][idx]
                    + C_lds[4][idx] + C_lds[5][idx] + C_lds[6][idx] + C_lds[7][idx];
      Ch[(size_t)(rowbase + rg*16 + m)*128 + d] = v;
      if (d == 0){
        const float den = dn_lds[0][rg*16+m] + dn_lds[1][rg*16+m] + dn_lds[2][rg*16+m]
                        + dn_lds[3][rg*16+m] + dn_lds[4][rg*16+m] + dn_lds[5][rg*16+m]
                        + dn_lds[6][rg*16+m] + dn_lds[7][rg*16+m];
        dnpart[half*NROW + rowbase + rg*16 + m] = den;
      }
    }
    __syncthreads();
  }
}

// ---------------------------------------------------------------------------
// K6b: merge halves: emb = elu( (C0+C1) / (dn0+dn1) ), k-packed bf16 out.
// ---------------------------------------------------------------------------
__global__ __launch_bounds__(256) void k_merge(
    const float* __restrict__ Cpart, const float* __restrict__ dnpart,
    unsigned short* __restrict__ emb_p)
{
  const int tid = threadIdx.x;
  const int rowbase = blockIdx.x * 16;
  const float* C0 = Cpart;
  const float* C1 = Cpart + (size_t)NROW * 128;
  #pragma unroll
  for (int k=0;k<8;++k){
    const int idx = tid + k*256;       // 16 rows x 128 d
    const int m = idx >> 7;
    const int d = idx & 127;
    const int row = rowbase + m;
    const float den = dnpart[row] + dnpart[NROW + row];
    float v = (C0[(size_t)row*128 + d] + C1[(size_t)row*128 + d]) / den;
    v = (v > 0.f) ? v : (__expf(v) - 1.f);   // elu
    emb_p[(size_t)(d >> 3)*65536 + (size_t)row*8 + (d & 7)] = f2b(v);
  }
}

// ---------------------------------------------------------------------------
// K7: con_adj = emb @ emb^T. emb_p k-packed: (k>>3)*65536 + row*8 + (k&7).
// ---------------------------------------------------------------------------
__global__ __launch_bounds__(256) void k_out(
    const unsigned short* __restrict__ emb_p, const int* __restrict__ flag,
    void* __restrict__ d_out)
{
  const int tid  = threadIdx.x;
  const int lane = tid & 63, wv = tid >> 6;
  const int quad = lane >> 4, nn = lane & 15;
  const int i0 = blockIdx.y * 128 + wv * 32;
  const int j0 = blockIdx.x * 64;

  f32x4 acc[2][4];
  #pragma unroll
  for (int a=0;a<2;++a)
    #pragma unroll
    for (int b=0;b<4;++b) acc[a][b] = (f32x4){0.f,0.f,0.f,0.f};

  #pragma unroll
  for (int ks=0; ks<4; ++ks){
    const int kb = ks*32 + quad*8;
    const unsigned short* base = emb_p + (size_t)(kb >> 3)*65536;
    bf16x8 a0 = *(const bf16x8*)(base + (size_t)(i0 + nn)*8);
    bf16x8 a1 = *(const bf16x8*)(base + (size_t)(i0 + 16 + nn)*8);
    #pragma unroll
    for (int t=0;t<4;++t){
      bf16x8 b = *(const bf16x8*)(base + (size_t)(j0 + t*16 + nn)*8);
      acc[0][t] = __builtin_amdgcn_mfma_f32_16x16x32_bf16(a0, b, acc[0][t], 0, 0, 0);
      acc[1][t] = __builtin_amdgcn_mfma_f32_16x16x32_bf16(a1, b, acc[1][t], 0, 0, 0);
    }
  }

  const int isf32 = flag[0];
  if (isf32){
    float* out = (float*)d_out;
    #pragma unroll
    for (int mi=0; mi<2; ++mi)
      #pragma unroll
      for (int t=0;t<4;++t)
        #pragma unroll
        for (int r=0;r<4;++r)
          out[(size_t)(i0 + mi*16 + quad*4 + r)*NROW + j0 + t*16 + nn] = acc[mi][t][r];
  } else {
    unsigned short* out = (unsigned short*)d_out;
    #pragma unroll
    for (int mi=0; mi<2; ++mi)
      #pragma unroll
      for (int t=0;t<4;++t)
        #pragma unroll
        for (int r=0;r<4;++r)
          out[(size_t)(i0 + mi*16 + quad*4 + r)*NROW + j0 + t*16 + nn] = f2b(acc[mi][t][r]);
  }
}

// ---------------------------------------------------------------------------
extern "C" void kernel_launch(void* const* d_in, const int* in_sizes, int n_in,
                              void* d_out, int out_size, void* d_ws, size_t ws_size,
                              hipStream_t stream)
{
  (void)in_sizes; (void)n_in; (void)out_size; (void)ws_size;
  const void* x        = d_in[0];
  const void* adj      = d_in[1];
  const void* fea_W    = d_in[2];
  const void* fea_b    = d_in[3];
  const void* gat_W    = d_in[4];
  const void* gat_a    = d_in[5];
  const void* enc_W_ih = d_in[6];
  const void* enc_b_ih = d_in[8];
  const void* enc_b_hh = d_in[9];
  const void* dec_W_ih = d_in[10];
  const void* dec_b_ih = d_in[12];
  const void* dec_b_hh = d_in[13];

  char* ws = (char*)d_ws;
  unsigned short* Whb_p   = (unsigned short*)ws;                 // 2 MB  Wh k-packed bf16
  unsigned short* emb_p   = (unsigned short*)(ws + (2u<<20));    // 2 MB  emb k-packed bf16
  unsigned short* xb      = (unsigned short*)(ws + (4u<<20));    // 2 MB  x bf16
  unsigned short* h_enc_b = (unsigned short*)(ws + (6u<<20));    // 1 MB  h_enc bf16
  unsigned char*  mask8   = (unsigned char*) (ws + (7u<<20));    // 8 MB  adj bitmask
  float* s1    = (float*)(ws + (15u<<20));                       // 32 KB
  float* s2    = (float*)(ws + (15u<<20) + 32768);               // 32 KB
  unsigned short* encWb = (unsigned short*)(ws + (15u<<20) + 65536);          // 64 KB
  unsigned short* decWb = (unsigned short*)(ws + (15u<<20) + 65536 + 65536);  // 64 KB
  int* flag = (int*)(ws + (15u<<20) + 3*65536);
  float* Cpart  = (float*)(ws + (16u<<20));                      // 8 MB  partial C (2 halves)
  float* dnpart = (float*)(ws + (24u<<20));                      // 64 KB partial denominators

  k_probe<<<1, 64, 0, stream>>>((const unsigned short*)x, flag);
  k_cvt<<<256, 256, 0, stream>>>(enc_W_ih, dec_W_ih, flag, encWb, decWb);
  k_feamask<<<NROW, 256, 0, stream>>>(x, adj, fea_W, fea_b, gat_W, gat_a, flag,
                                      Whb_p, s1, s2, xb, mask8);
  k_enc2<<<256, 256, 0, stream>>>(xb, encWb, enc_b_ih, enc_b_hh, flag, h_enc_b);
  k_dec2<<<512, 256, 0, stream>>>(h_enc_b, decWb, dec_b_ih, dec_b_hh, flag, d_out);
  k_attn32s<<<512, 512, 0, stream>>>(mask8, Whb_p, s1, s2, Cpart, dnpart);
  k_merge<<<512, 256, 0, stream>>>(Cpart, dnpart, emb_p);
  k_out<<<dim3(128, 64), 256, 0, stream>>>(emb_p, flag, d_out);
}